// Round 12
// baseline (248.341 us; speedup 1.0000x reference)
//
#include <hip/hip_runtime.h>
#include <hip/hip_bf16.h>

#define N_NODES 50000
#define N_PAD   50048   // padded to multiple of 64 rows
#define N_EDGES 800000
#define N_GRAPHS 64
#define D 90
#define HS  96    // dense h row stride (bf16)
#define HSD 48    // dense h row stride (dwords)
#define HS8 24    // fp8 h row stride (dwords)
#define SC  192   // Wcat row stride (bf16): [Wl(96) | Wr(96)]

#define NBUCKETS 196    // ceil(N_NODES/256): 256 nodes per bucket
#define BSHIFT 8
#define BIN_EPB 4096    // edges per block in hist/bin

typedef __attribute__((ext_vector_type(8))) short bf16x8;
typedef __attribute__((ext_vector_type(4))) float f32x4;
typedef __attribute__((ext_vector_type(2))) float f32x2;

__device__ __forceinline__ float bflo(unsigned int v) { return __uint_as_float(v << 16); }
__device__ __forceinline__ float bfhi(unsigned int v) { return __uint_as_float(v & 0xffff0000u); }
__device__ __forceinline__ unsigned short bf16bits(float f) {
    __hip_bfloat16 b = __float2bfloat16(f);
    return *(unsigned short*)&b;
}
__device__ __forceinline__ unsigned int pack2bf(float lo, float hi) {
    return (unsigned int)bf16bits(lo) | ((unsigned int)bf16bits(hi) << 16);
}
// fp8 e4m3 HW convert (gfx950 fp8-conversion-insts); pack+unpack use the same
// HW format, so the roundtrip is self-consistent.
__device__ __forceinline__ unsigned char f32_to_fp8(float v) {
    int pk = __builtin_amdgcn_cvt_pk_fp8_f32(v, v, 0, false);
    return (unsigned char)(pk & 0xff);
}

// ---------------- fused head: x->bf16 + fp8 h, W pack, zero-init ----------------
__global__ void k_prep(const float* __restrict__ x, __hip_bfloat16* __restrict__ h0,
                       unsigned char* __restrict__ h8,
                       const float* __restrict__ w1l, const float* __restrict__ w1r,
                       const float* __restrict__ w2l, const float* __restrict__ w2r,
                       const float* __restrict__ w3l, const float* __restrict__ w3r,
                       __hip_bfloat16* __restrict__ Wcat,
                       int* __restrict__ bcnt, float* __restrict__ pooled) {
    int idx = blockIdx.x * 256 + threadIdx.x;
    if (idx < N_PAD * HS) {
        int n = idx / HS, k = idx - n * HS;
        float v = (n < N_NODES && k < D) ? x[n * D + k] : 0.f;
        h0[idx] = __float2bfloat16(v);
        h8[idx] = f32_to_fp8(v);
    }
    if (idx < 3 * 96 * SC) {
        const int per = 96 * SC;
        int layer = idx / per, rem = idx - layer * per;
        int j = rem / SC, k = rem - j * SC;
        const float* wl = (layer == 0) ? w1l : (layer == 1) ? w2l : w3l;
        const float* wr = (layer == 0) ? w1r : (layer == 1) ? w2r : w3r;
        float v = 0.f;
        if (j < D) {
            if (k < 96) { if (k < D) v = wl[j * D + k]; }
            else        { int kk = k - 96; if (kk < D) v = wr[j * D + kk]; }
        }
        Wcat[idx] = __float2bfloat16(v);
    }
    if (idx < N_GRAPHS * D + N_GRAPHS) pooled[idx] = 0.f;
    if (idx < NBUCKETS) bcnt[idx] = 0;
}

// ---------------- CSR build: bucket-local, write-coalesced ----------------
__global__ void k_hist(const int* __restrict__ dst, int* __restrict__ bcnt) {
    __shared__ int h[NBUCKETS];
    int t = threadIdx.x;
    for (int i = t; i < NBUCKETS; i += 256) h[i] = 0;
    __syncthreads();
    int base = blockIdx.x * BIN_EPB;
    int lim = base + BIN_EPB; if (lim > N_EDGES) lim = N_EDGES;
    for (int e = base + t; e < lim; e += 256)
        atomicAdd(&h[dst[e] >> BSHIFT], 1);
    __syncthreads();
    for (int i = t; i < NBUCKETS; i += 256) {
        int c = h[i];
        if (c) atomicAdd(&bcnt[i], c);
    }
}

__global__ void k_bscan(const int* __restrict__ bcnt, int* __restrict__ bbase,
                        int* __restrict__ bcursor) {
    __shared__ int s[256];
    int t = threadIdx.x;
    int v = (t < NBUCKETS) ? bcnt[t] : 0;
    s[t] = v; __syncthreads();
    for (int o = 1; o < 256; o <<= 1) {
        int x = (t >= o) ? s[t - o] : 0;
        __syncthreads();
        s[t] += x;
        __syncthreads();
    }
    int excl = s[t] - v;
    if (t < NBUCKETS) { bbase[t] = excl; bcursor[t] = excl; }
    if (t == 255) bbase[NBUCKETS] = s[255];   // total = N_EDGES
}

__global__ __launch_bounds__(256) void k_bin(const int* __restrict__ src,
                                             const int* __restrict__ dst,
                                             int* __restrict__ bcursor,
                                             unsigned int* __restrict__ ebuf) {
    __shared__ int h[NBUCKETS];
    __shared__ int gb[NBUCKETS];
    int t = threadIdx.x;
    for (int i = t; i < NBUCKETS; i += 256) h[i] = 0;
    __syncthreads();
    int base = blockIdx.x * BIN_EPB;
    int sv[16], dv[16], rv[16];
    #pragma unroll
    for (int i = 0; i < 16; ++i) {
        int e = base + i * 256 + t;
        if (e < N_EDGES) {
            sv[i] = src[e];
            dv[i] = dst[e];
            rv[i] = atomicAdd(&h[dv[i] >> BSHIFT], 1);
        }
    }
    __syncthreads();
    for (int i = t; i < NBUCKETS; i += 256)
        gb[i] = h[i] ? atomicAdd(&bcursor[i], h[i]) : 0;
    __syncthreads();
    #pragma unroll
    for (int i = 0; i < 16; ++i) {
        int e = base + i * 256 + t;
        if (e < N_EDGES) {
            int b = dv[i] >> BSHIFT;
            ebuf[gb[b] + rv[i]] = (unsigned int)sv[i] | ((unsigned int)(dv[i] & 255) << 16);
        }
    }
}

__global__ __launch_bounds__(256) void k_fill2(const unsigned int* __restrict__ ebuf,
                                               const int* __restrict__ bbase,
                                               int* __restrict__ off,
                                               int* __restrict__ csr) {
    __shared__ int lcnt[256];
    __shared__ int excl[256];
    int t = threadIdx.x;
    int n0 = blockIdx.x << BSHIFT;
    int ebeg = bbase[blockIdx.x], eend = bbase[blockIdx.x + 1];
    lcnt[t] = 0;
    __syncthreads();
    for (int e = ebeg + t; e < eend; e += 256)
        atomicAdd(&lcnt[ebuf[e] >> 16], 1);
    __syncthreads();
    int v = lcnt[t];
    excl[t] = v; __syncthreads();
    for (int o = 1; o < 256; o <<= 1) {
        int x = (t >= o) ? excl[t - o] : 0;
        __syncthreads();
        excl[t] += x;
        __syncthreads();
    }
    excl[t] -= v;           // exclusive prefix within bucket
    int n = n0 + t;
    if (n <= N_NODES) off[n] = ebeg + excl[t];
    lcnt[t] = 0;
    __syncthreads();
    for (int e = ebeg + t; e < eend; e += 256) {
        unsigned int u = ebuf[e];
        int li = u >> 16;
        int r = atomicAdd(&lcnt[li], 1);
        csr[ebeg + excl[li] + r] = (int)(u & 0xFFFFu);
    }
}

// ---------------- fused SAGE layer: fp8 gather-agg (LDS) + MFMA + bias + ReLU ----------------
// block = 64 nodes, 512 threads (8 waves).
// Phase 1: wave w aggregates nodes [blk*64 + 8w, +8) from the fp8 shadow copy:
//          8 lanes/edge x 8 edge-groups, 3 dwords (12 fp8) per lane per edge,
//          HW cvt_pk_f32_fp8 unpack, shfl-fold, bf16 into LDS aggT[64][52].
// Phase 2: wave w = (strip w&3, col-half w>>2): 16 rows x 48 cols MFMA.
//          A k<96 from LDS (agg), k>=96 from global bf16 h (root path).
// Epilogue: write bf16 hout + fp8 shadow hout8.
__global__ __launch_bounds__(512) void k_layer(
    const unsigned int* __restrict__ hin,    // [N_PAD][48] dwords (bf16 h)
    const unsigned int* __restrict__ hin8,   // [N_PAD][24] dwords (fp8 h)
    const __hip_bfloat16* __restrict__ Wcat, // [96][192]
    const float* __restrict__ bias,          // [90]
    const int* __restrict__ off, const int* __restrict__ csr,
    __hip_bfloat16* __restrict__ hout,       // [N_PAD][96]
    unsigned char* __restrict__ hout8)       // [N_PAD][96]
{
    __shared__ unsigned int aggT[64][52];
    __shared__ float biasPad[96];
    int tid = threadIdx.x;
    if (tid < 96) biasPad[tid] = (tid < D) ? bias[tid] : 0.f;
    int w = tid >> 6, lane = tid & 63;

    // ---- phase 1: fp8 aggregation ----
    int eg = lane >> 3, sl = lane & 7;
    int col8 = 3 * sl;        // dword offset in 24-dword fp8 row (12 cols/lane)
    for (int i = 0; i < 8; ++i) {
        int local = w * 8 + i;
        int node = blockIdx.x * 64 + local;
        int beg = 0, end = 0;
        if (node < N_NODES) { beg = off[node]; end = off[node + 1]; }
        float a[12];
        #pragma unroll
        for (int q = 0; q < 12; ++q) a[q] = 0.f;

        int e = beg + eg;
        for (; e + 8 < end; e += 16) {
            int sA = csr[e], sB = csr[e + 8];
            const unsigned int* pA = &hin8[sA * HS8 + col8];
            const unsigned int* pB = &hin8[sB * HS8 + col8];
            unsigned int u[3], v[3];
            #pragma unroll
            for (int q = 0; q < 3; ++q) u[q] = pA[q];
            #pragma unroll
            for (int q = 0; q < 3; ++q) v[q] = pB[q];
            #pragma unroll
            for (int q = 0; q < 3; ++q) {
                f32x2 lo = __builtin_amdgcn_cvt_pk_f32_fp8((int)u[q], false);
                f32x2 hi = __builtin_amdgcn_cvt_pk_f32_fp8((int)u[q], true);
                a[4 * q]     += lo.x; a[4 * q + 1] += lo.y;
                a[4 * q + 2] += hi.x; a[4 * q + 3] += hi.y;
            }
            #pragma unroll
            for (int q = 0; q < 3; ++q) {
                f32x2 lo = __builtin_amdgcn_cvt_pk_f32_fp8((int)v[q], false);
                f32x2 hi = __builtin_amdgcn_cvt_pk_f32_fp8((int)v[q], true);
                a[4 * q]     += lo.x; a[4 * q + 1] += lo.y;
                a[4 * q + 2] += hi.x; a[4 * q + 3] += hi.y;
            }
        }
        if (e < end) {
            const unsigned int* pA = &hin8[csr[e] * HS8 + col8];
            unsigned int u[3];
            #pragma unroll
            for (int q = 0; q < 3; ++q) u[q] = pA[q];
            #pragma unroll
            for (int q = 0; q < 3; ++q) {
                f32x2 lo = __builtin_amdgcn_cvt_pk_f32_fp8((int)u[q], false);
                f32x2 hi = __builtin_amdgcn_cvt_pk_f32_fp8((int)u[q], true);
                a[4 * q]     += lo.x; a[4 * q + 1] += lo.y;
                a[4 * q + 2] += hi.x; a[4 * q + 3] += hi.y;
            }
        }

        #pragma unroll
        for (int m = 8; m <= 32; m <<= 1) {
            #pragma unroll
            for (int q = 0; q < 12; ++q) a[q] += __shfl_xor(a[q], m);
        }
        if (eg == 0) {
            float inv = 1.0f / fmaxf((float)(end - beg), 1.0f);
            #pragma unroll
            for (int q = 0; q < 6; ++q) {
                int c0 = 12 * sl + 2 * q;
                float lo = (c0     < D) ? a[2 * q]     * inv : 0.f;
                float hi = (c0 + 1 < D) ? a[2 * q + 1] * inv : 0.f;
                aggT[local][6 * sl + q] = pack2bf(lo, hi);
            }
        }
    }
    __syncthreads();

    // ---- phase 2: MFMA ----
    int w4 = w & 3, half = w >> 2;
    int mrow = lane & 15, kg = lane >> 4;
    int r0 = blockIdx.x * 64 + w4 * 16;
    int lrow = w4 * 16 + mrow;
    const short* Wp = (const short*)Wcat;
    const short* Hs = (const short*)hin;

    f32x4 acc[3];
    #pragma unroll
    for (int t = 0; t < 3; ++t) {
        int j = (half * 3 + t) * 16 + mrow;
        float b = biasPad[j];
        acc[t] = (f32x4){b, b, b, b};
    }

    #pragma unroll
    for (int ks = 0; ks < 6; ++ks) {
        bf16x8 afr;
        if (ks < 3) afr = *(const bf16x8*)&aggT[lrow][ks * 16 + kg * 4];
        else        afr = *(const bf16x8*)&Hs[(r0 + mrow) * HS + (ks - 3) * 32 + kg * 8];
        #pragma unroll
        for (int t = 0; t < 3; ++t) {
            int j = (half * 3 + t) * 16 + mrow;
            bf16x8 bfr = *(const bf16x8*)&Wp[j * SC + ks * 32 + kg * 8];
            acc[t] = __builtin_amdgcn_mfma_f32_16x16x32_bf16(afr, bfr, acc[t], 0, 0, 0);
        }
    }

    // C/D layout (m89): col = lane&15, row = (lane>>4)*4 + v
    int orow = r0 + kg * 4;
    #pragma unroll
    for (int t = 0; t < 3; ++t) {
        int j = (half * 3 + t) * 16 + mrow;
        #pragma unroll
        for (int v = 0; v < 4; ++v) {
            float val = (j < D) ? fmaxf(acc[t][v], 0.f) : 0.f;
            hout[(orow + v) * HS + j] = __float2bfloat16(val);
            hout8[(orow + v) * HS + j] = f32_to_fp8(val);
        }
    }
}

// ---------------- graph mean pool: segmented reduction (batch sorted) ----------------
#define POOL_WAVES 4096
__global__ void k_pool(const unsigned int* __restrict__ h, const int* __restrict__ batch,
                       float* __restrict__ pooled, float* __restrict__ cntg) {
    int wid  = (blockIdx.x * blockDim.x + threadIdx.x) >> 6;
    int lane = threadIdx.x & 63;
    const int per = (N_NODES + POOL_WAVES - 1) / POOL_WAVES;  // 13
    int beg = wid * per;
    int end = beg + per; if (end > N_NODES) end = N_NODES;
    if (beg >= end) return;
    int cur = batch[beg];
    float a0 = 0.f, a1 = 0.f, c = 0.f;
    for (int n = beg; n < end; ++n) {
        int g = batch[n];
        if (g != cur) {
            if (lane < 45) {
                atomicAdd(&pooled[cur * D + 2 * lane], a0);
                atomicAdd(&pooled[cur * D + 2 * lane + 1], a1);
            }
            if (lane == 0) atomicAdd(&cntg[cur], c);
            a0 = a1 = c = 0.f;
            cur = g;
        }
        if (lane < 45) {
            unsigned int v = h[n * HSD + lane];
            a0 += bflo(v);
            a1 += bfhi(v);
        }
        c += 1.f;
    }
    if (lane < 45) {
        atomicAdd(&pooled[cur * D + 2 * lane], a0);
        atomicAdd(&pooled[cur * D + 2 * lane + 1], a1);
    }
    if (lane == 0) atomicAdd(&cntg[cur], c);
}

// ---------------- final MLP (single block) ----------------
__global__ void k_mlp(const float* __restrict__ pooled, const float* __restrict__ cntg,
                      const float* __restrict__ Wf1, const float* __restrict__ bf1,
                      const float* __restrict__ Wf2, const float* __restrict__ bf2,
                      float* __restrict__ outp) {
    __shared__ float P[N_GRAPHS][92];
    __shared__ float H4[N_GRAPHS][32];
    int tid = threadIdx.x;
    for (int idx = tid; idx < N_GRAPHS * D; idx += 256) {
        int g = idx / D, d = idx - g * D;
        P[g][d] = pooled[idx] / fmaxf(cntg[g], 1.0f);
    }
    __syncthreads();
    for (int idx = tid; idx < N_GRAPHS * 32; idx += 256) {
        int g = idx >> 5, c = idx & 31;
        float acc = bf1[c];
        for (int d = 0; d < D; ++d) acc += P[g][d] * Wf1[c * D + d];
        H4[g][c] = fmaxf(acc, 0.f);
    }
    __syncthreads();
    if (tid < N_GRAPHS) {
        float acc = bf2[0];
        #pragma unroll
        for (int c = 0; c < 32; ++c) acc += H4[tid][c] * Wf2[c];
        outp[tid] = acc;
    }
}

extern "C" void kernel_launch(void* const* d_in, const int* in_sizes, int n_in,
                              void* d_out, int out_size, void* d_ws, size_t ws_size,
                              hipStream_t stream) {
    const float* x    = (const float*)d_in[0];
    const int*   ei   = (const int*)d_in[1];
    const int*   batch= (const int*)d_in[2];
    const float* W1l  = (const float*)d_in[3];
    const float* b1   = (const float*)d_in[4];
    const float* W1r  = (const float*)d_in[5];
    const float* W2l  = (const float*)d_in[6];
    const float* b2   = (const float*)d_in[7];
    const float* W2r  = (const float*)d_in[8];
    const float* W3l  = (const float*)d_in[9];
    const float* b3   = (const float*)d_in[10];
    const float* W3r  = (const float*)d_in[11];
    const float* Wf1  = (const float*)d_in[12];
    const float* bf1  = (const float*)d_in[13];
    const float* Wf2  = (const float*)d_in[14];
    const float* bf2  = (const float*)d_in[15];
    const int* srcI = ei;
    const int* dstI = ei + N_EDGES;

    char* base = (char*)d_ws;
    size_t o = 0;
    auto alloc = [&](size_t bytes) -> void* {
        void* p = base + o;
        o = (o + bytes + 255) & ~(size_t)255;
        return p;
    };
    int*   bcnt    = (int*)alloc((size_t)NBUCKETS * 4);
    int*   bbase   = (int*)alloc((size_t)(NBUCKETS + 1) * 4);
    int*   bcursor = (int*)alloc((size_t)NBUCKETS * 4);
    int*   off     = (int*)alloc((size_t)(N_NODES + 1) * 4);
    unsigned int* ebuf = (unsigned int*)alloc((size_t)N_EDGES * 4);
    int*   csr     = (int*)alloc((size_t)N_EDGES * 4);
    __hip_bfloat16* hA = (__hip_bfloat16*)alloc((size_t)N_PAD * HS * 2);
    __hip_bfloat16* hB = (__hip_bfloat16*)alloc((size_t)N_PAD * HS * 2);
    unsigned char* h8A = (unsigned char*)alloc((size_t)N_PAD * HS);
    unsigned char* h8B = (unsigned char*)alloc((size_t)N_PAD * HS);
    __hip_bfloat16* Wcat = (__hip_bfloat16*)alloc((size_t)3 * 96 * SC * 2);
    float* pooled = (float*)alloc((size_t)(N_GRAPHS * D + N_GRAPHS) * 4);
    float* cntg   = pooled + N_GRAPHS * D;

    // fused head: cvt (bf16 + fp8) + W pack + zero-init
    k_prep<<<(N_PAD * HS + 255) / 256, 256, 0, stream>>>(
        x, hA, h8A, W1l, W1r, W2l, W2r, W3l, W3r, Wcat, bcnt, pooled);

    const int EB = (N_EDGES + BIN_EPB - 1) / BIN_EPB;  // 196
    k_hist<<<EB, 256, 0, stream>>>(dstI, bcnt);
    k_bscan<<<1, 256, 0, stream>>>(bcnt, bbase, bcursor);
    k_bin<<<EB, 256, 0, stream>>>(srcI, dstI, bcursor, ebuf);
    k_fill2<<<NBUCKETS, 256, 0, stream>>>(ebuf, bbase, off, csr);

    const int LAYER_BLOCKS = N_PAD / 64;   // 782

    unsigned int* hAu  = (unsigned int*)hA;
    unsigned int* hBu  = (unsigned int*)hB;
    unsigned int* h8Au = (unsigned int*)h8A;
    unsigned int* h8Bu = (unsigned int*)h8B;

    k_layer<<<LAYER_BLOCKS, 512, 0, stream>>>(hAu, h8Au, Wcat,            b1, off, csr, hB, h8B);
    k_layer<<<LAYER_BLOCKS, 512, 0, stream>>>(hBu, h8Bu, Wcat +  96 * SC, b2, off, csr, hA, h8A);
    k_layer<<<LAYER_BLOCKS, 512, 0, stream>>>(hAu, h8Au, Wcat + 192 * SC, b3, off, csr, hB, h8B);

    k_pool<<<POOL_WAVES / 4, 256, 0, stream>>>(hBu, batch, pooled, cntg);
    k_mlp<<<1, 256, 0, stream>>>(pooled, cntg, Wf1, bf1, Wf2, bf2, (float*)d_out);
}

// Round 13
// 217.412 us; speedup vs baseline: 1.1423x; 1.1423x over previous
//
#include <hip/hip_runtime.h>
#include <hip/hip_bf16.h>

#define N_NODES 50000
#define N_PAD   50048   // padded to multiple of 64 rows
#define N_EDGES 800000
#define N_GRAPHS 64
#define D 90
#define HS  96    // dense h row stride (bf16)
#define HSD 48    // dense h row stride (dwords)
#define SC  192   // Wcat row stride (bf16): [Wl(96) | Wr(96)]

#define NBUCKETS 196    // ceil(N_NODES/256): 256 nodes per bucket
#define BSHIFT 8
#define BIN_EPB 4096    // edges per block in hist/bin

typedef __attribute__((ext_vector_type(8))) short bf16x8;
typedef __attribute__((ext_vector_type(4))) float f32x4;

__device__ __forceinline__ float bflo(unsigned int v) { return __uint_as_float(v << 16); }
__device__ __forceinline__ float bfhi(unsigned int v) { return __uint_as_float(v & 0xffff0000u); }
__device__ __forceinline__ unsigned short bf16bits(float f) {
    __hip_bfloat16 b = __float2bfloat16(f);
    return *(unsigned short*)&b;
}
__device__ __forceinline__ unsigned int pack2bf(float lo, float hi) {
    return (unsigned int)bf16bits(lo) | ((unsigned int)bf16bits(hi) << 16);
}

// ---------------- fused head: x->bf16 dense h, W pack, zero-init ----------------
__global__ void k_prep(const float* __restrict__ x, __hip_bfloat16* __restrict__ h0,
                       const float* __restrict__ w1l, const float* __restrict__ w1r,
                       const float* __restrict__ w2l, const float* __restrict__ w2r,
                       const float* __restrict__ w3l, const float* __restrict__ w3r,
                       __hip_bfloat16* __restrict__ Wcat,
                       int* __restrict__ bcnt, float* __restrict__ pooled) {
    int idx = blockIdx.x * 256 + threadIdx.x;
    if (idx < N_PAD * HS) {
        int n = idx / HS, k = idx - n * HS;
        float v = (n < N_NODES && k < D) ? x[n * D + k] : 0.f;
        h0[idx] = __float2bfloat16(v);
    }
    if (idx < 3 * 96 * SC) {
        const int per = 96 * SC;
        int layer = idx / per, rem = idx - layer * per;
        int j = rem / SC, k = rem - j * SC;
        const float* wl = (layer == 0) ? w1l : (layer == 1) ? w2l : w3l;
        const float* wr = (layer == 0) ? w1r : (layer == 1) ? w2r : w3r;
        float v = 0.f;
        if (j < D) {
            if (k < 96) { if (k < D) v = wl[j * D + k]; }
            else        { int kk = k - 96; if (kk < D) v = wr[j * D + kk]; }
        }
        Wcat[idx] = __float2bfloat16(v);
    }
    if (idx < N_GRAPHS * D + N_GRAPHS) pooled[idx] = 0.f;
    if (idx < NBUCKETS) bcnt[idx] = 0;
}

// ---------------- CSR build: bucket-local, write-coalesced ----------------
__global__ void k_hist(const int* __restrict__ dst, int* __restrict__ bcnt) {
    __shared__ int h[NBUCKETS];
    int t = threadIdx.x;
    for (int i = t; i < NBUCKETS; i += 256) h[i] = 0;
    __syncthreads();
    int base = blockIdx.x * BIN_EPB;
    int lim = base + BIN_EPB; if (lim > N_EDGES) lim = N_EDGES;
    for (int e = base + t; e < lim; e += 256)
        atomicAdd(&h[dst[e] >> BSHIFT], 1);
    __syncthreads();
    for (int i = t; i < NBUCKETS; i += 256) {
        int c = h[i];
        if (c) atomicAdd(&bcnt[i], c);
    }
}

__global__ void k_bscan(const int* __restrict__ bcnt, int* __restrict__ bbase,
                        int* __restrict__ bcursor) {
    __shared__ int s[256];
    int t = threadIdx.x;
    int v = (t < NBUCKETS) ? bcnt[t] : 0;
    s[t] = v; __syncthreads();
    for (int o = 1; o < 256; o <<= 1) {
        int x = (t >= o) ? s[t - o] : 0;
        __syncthreads();
        s[t] += x;
        __syncthreads();
    }
    int excl = s[t] - v;
    if (t < NBUCKETS) { bbase[t] = excl; bcursor[t] = excl; }
    if (t == 255) bbase[NBUCKETS] = s[255];   // total = N_EDGES
}

__global__ __launch_bounds__(256) void k_bin(const int* __restrict__ src,
                                             const int* __restrict__ dst,
                                             int* __restrict__ bcursor,
                                             unsigned int* __restrict__ ebuf) {
    __shared__ int h[NBUCKETS];
    __shared__ int gb[NBUCKETS];
    int t = threadIdx.x;
    for (int i = t; i < NBUCKETS; i += 256) h[i] = 0;
    __syncthreads();
    int base = blockIdx.x * BIN_EPB;
    int sv[16], dv[16], rv[16];
    #pragma unroll
    for (int i = 0; i < 16; ++i) {
        int e = base + i * 256 + t;
        if (e < N_EDGES) {
            sv[i] = src[e];
            dv[i] = dst[e];
            rv[i] = atomicAdd(&h[dv[i] >> BSHIFT], 1);
        }
    }
    __syncthreads();
    for (int i = t; i < NBUCKETS; i += 256)
        gb[i] = h[i] ? atomicAdd(&bcursor[i], h[i]) : 0;
    __syncthreads();
    #pragma unroll
    for (int i = 0; i < 16; ++i) {
        int e = base + i * 256 + t;
        if (e < N_EDGES) {
            int b = dv[i] >> BSHIFT;
            ebuf[gb[b] + rv[i]] = (unsigned int)sv[i] | ((unsigned int)(dv[i] & 255) << 16);
        }
    }
}

__global__ __launch_bounds__(256) void k_fill2(const unsigned int* __restrict__ ebuf,
                                               const int* __restrict__ bbase,
                                               int* __restrict__ off,
                                               int* __restrict__ csr) {
    __shared__ int lcnt[256];
    __shared__ int excl[256];
    int t = threadIdx.x;
    int n0 = blockIdx.x << BSHIFT;
    int ebeg = bbase[blockIdx.x], eend = bbase[blockIdx.x + 1];
    lcnt[t] = 0;
    __syncthreads();
    for (int e = ebeg + t; e < eend; e += 256)
        atomicAdd(&lcnt[ebuf[e] >> 16], 1);
    __syncthreads();
    int v = lcnt[t];
    excl[t] = v; __syncthreads();
    for (int o = 1; o < 256; o <<= 1) {
        int x = (t >= o) ? excl[t - o] : 0;
        __syncthreads();
        excl[t] += x;
        __syncthreads();
    }
    excl[t] -= v;           // exclusive prefix within bucket
    int n = n0 + t;
    if (n <= N_NODES) off[n] = ebeg + excl[t];
    lcnt[t] = 0;
    __syncthreads();
    for (int e = ebeg + t; e < eend; e += 256) {
        unsigned int u = ebuf[e];
        int li = u >> 16;
        int r = atomicAdd(&lcnt[li], 1);
        csr[ebeg + excl[li] + r] = (int)(u & 0xFFFFu);
    }
}

// ---------------- fused SAGE layer: node-parallel gather + MFMA + bias + ReLU ----------------
// block = 32 nodes, 256 threads (4 waves).
// Phase 1: each 8-lane group owns ONE node (8 concurrent latency chains per wave,
//          vs 1 in the old whole-wave-per-node scheme). Lane sl covers cols
//          [12sl,12sl+12): 6 dwords per edge. Serial edge walk, unroll 4
//          -> 24 outstanding dwords per group. No shuffle; direct LDS write.
// Phase 2: wave w = (strip w&1, col-half w>>1): 16 rows x 48 cols, 3 col-tiles x
//          6 k-steps MFMA. A k<96 from LDS (agg), k>=96 from global bf16 h.
__global__ __launch_bounds__(256) void k_layer(
    const unsigned int* __restrict__ hin,   // [N_PAD][48] dwords (dense bf16 h)
    const __hip_bfloat16* __restrict__ Wcat,// [96][192]
    const float* __restrict__ bias,         // [90]
    const int* __restrict__ off, const int* __restrict__ csr,
    __hip_bfloat16* __restrict__ hout)      // [N_PAD][96]
{
    __shared__ unsigned int aggT[32][52];
    __shared__ float biasPad[96];
    int tid = threadIdx.x;
    if (tid < 96) biasPad[tid] = (tid < D) ? bias[tid] : 0.f;
    int w = tid >> 6, lane = tid & 63;

    // ---- phase 1: node-per-group aggregation ----
    int grp = lane >> 3, sl = lane & 7;
    int local = w * 8 + grp;               // node slot 0..31
    int node = blockIdx.x * 32 + local;
    int colw = 6 * sl;                     // dword offset in 48-dword row

    int beg = 0, end = 0;
    if (node < N_NODES) { beg = off[node]; end = off[node + 1]; }

    float a[12];
    #pragma unroll
    for (int q = 0; q < 12; ++q) a[q] = 0.f;

    int e = beg;
    for (; e + 4 <= end; e += 4) {
        int s0 = csr[e], s1 = csr[e + 1], s2 = csr[e + 2], s3 = csr[e + 3];
        const unsigned int* p0 = &hin[s0 * HSD + colw];
        const unsigned int* p1 = &hin[s1 * HSD + colw];
        const unsigned int* p2 = &hin[s2 * HSD + colw];
        const unsigned int* p3 = &hin[s3 * HSD + colw];
        unsigned int u0[6], u1[6], u2[6], u3[6];
        #pragma unroll
        for (int q = 0; q < 6; ++q) u0[q] = p0[q];
        #pragma unroll
        for (int q = 0; q < 6; ++q) u1[q] = p1[q];
        #pragma unroll
        for (int q = 0; q < 6; ++q) u2[q] = p2[q];
        #pragma unroll
        for (int q = 0; q < 6; ++q) u3[q] = p3[q];
        #pragma unroll
        for (int q = 0; q < 6; ++q) {
            a[2 * q]     += (bflo(u0[q]) + bflo(u1[q])) + (bflo(u2[q]) + bflo(u3[q]));
            a[2 * q + 1] += (bfhi(u0[q]) + bfhi(u1[q])) + (bfhi(u2[q]) + bfhi(u3[q]));
        }
    }
    for (; e < end; ++e) {
        const unsigned int* p0 = &hin[csr[e] * HSD + colw];
        unsigned int u0[6];
        #pragma unroll
        for (int q = 0; q < 6; ++q) u0[q] = p0[q];
        #pragma unroll
        for (int q = 0; q < 6; ++q) {
            a[2 * q]     += bflo(u0[q]);
            a[2 * q + 1] += bfhi(u0[q]);
        }
    }

    {
        float inv = 1.0f / fmaxf((float)(end - beg), 1.0f);
        #pragma unroll
        for (int q = 0; q < 6; ++q) {
            int c0 = 12 * sl + 2 * q;
            float lo = (c0     < D) ? a[2 * q]     * inv : 0.f;
            float hi = (c0 + 1 < D) ? a[2 * q + 1] * inv : 0.f;
            aggT[local][colw + q] = pack2bf(lo, hi);
        }
    }
    __syncthreads();

    // ---- phase 2: MFMA ----
    int w2 = w & 1, half = w >> 1;
    int mrow = lane & 15, kg = lane >> 4;
    int r0 = blockIdx.x * 32 + w2 * 16;
    int lrow = w2 * 16 + mrow;
    const short* Wp = (const short*)Wcat;
    const short* Hs = (const short*)hin;

    f32x4 acc[3];
    #pragma unroll
    for (int t = 0; t < 3; ++t) {
        int j = (half * 3 + t) * 16 + mrow;
        float b = biasPad[j];
        acc[t] = (f32x4){b, b, b, b};
    }

    #pragma unroll
    for (int ks = 0; ks < 6; ++ks) {
        bf16x8 afr;
        if (ks < 3) afr = *(const bf16x8*)&aggT[lrow][ks * 16 + kg * 4];
        else        afr = *(const bf16x8*)&Hs[(r0 + mrow) * HS + (ks - 3) * 32 + kg * 8];
        #pragma unroll
        for (int t = 0; t < 3; ++t) {
            int j = (half * 3 + t) * 16 + mrow;
            bf16x8 bfr = *(const bf16x8*)&Wp[j * SC + ks * 32 + kg * 8];
            acc[t] = __builtin_amdgcn_mfma_f32_16x16x32_bf16(afr, bfr, acc[t], 0, 0, 0);
        }
    }

    // C/D layout (m89): col = lane&15, row = (lane>>4)*4 + v
    int orow = r0 + kg * 4;
    #pragma unroll
    for (int t = 0; t < 3; ++t) {
        int j = (half * 3 + t) * 16 + mrow;
        #pragma unroll
        for (int v = 0; v < 4; ++v) {
            float val = (j < D) ? fmaxf(acc[t][v], 0.f) : 0.f;
            hout[(orow + v) * HS + j] = __float2bfloat16(val);
        }
    }
}

// ---------------- graph mean pool: segmented reduction (batch sorted) ----------------
#define POOL_WAVES 4096
__global__ void k_pool(const unsigned int* __restrict__ h, const int* __restrict__ batch,
                       float* __restrict__ pooled, float* __restrict__ cntg) {
    int wid  = (blockIdx.x * blockDim.x + threadIdx.x) >> 6;
    int lane = threadIdx.x & 63;
    const int per = (N_NODES + POOL_WAVES - 1) / POOL_WAVES;  // 13
    int beg = wid * per;
    int end = beg + per; if (end > N_NODES) end = N_NODES;
    if (beg >= end) return;
    int cur = batch[beg];
    float a0 = 0.f, a1 = 0.f, c = 0.f;
    for (int n = beg; n < end; ++n) {
        int g = batch[n];
        if (g != cur) {
            if (lane < 45) {
                atomicAdd(&pooled[cur * D + 2 * lane], a0);
                atomicAdd(&pooled[cur * D + 2 * lane + 1], a1);
            }
            if (lane == 0) atomicAdd(&cntg[cur], c);
            a0 = a1 = c = 0.f;
            cur = g;
        }
        if (lane < 45) {
            unsigned int v = h[n * HSD + lane];
            a0 += bflo(v);
            a1 += bfhi(v);
        }
        c += 1.f;
    }
    if (lane < 45) {
        atomicAdd(&pooled[cur * D + 2 * lane], a0);
        atomicAdd(&pooled[cur * D + 2 * lane + 1], a1);
    }
    if (lane == 0) atomicAdd(&cntg[cur], c);
}

// ---------------- final MLP (single block) ----------------
__global__ void k_mlp(const float* __restrict__ pooled, const float* __restrict__ cntg,
                      const float* __restrict__ Wf1, const float* __restrict__ bf1,
                      const float* __restrict__ Wf2, const float* __restrict__ bf2,
                      float* __restrict__ outp) {
    __shared__ float P[N_GRAPHS][92];
    __shared__ float H4[N_GRAPHS][32];
    int tid = threadIdx.x;
    for (int idx = tid; idx < N_GRAPHS * D; idx += 256) {
        int g = idx / D, d = idx - g * D;
        P[g][d] = pooled[idx] / fmaxf(cntg[g], 1.0f);
    }
    __syncthreads();
    for (int idx = tid; idx < N_GRAPHS * 32; idx += 256) {
        int g = idx >> 5, c = idx & 31;
        float acc = bf1[c];
        for (int d = 0; d < D; ++d) acc += P[g][d] * Wf1[c * D + d];
        H4[g][c] = fmaxf(acc, 0.f);
    }
    __syncthreads();
    if (tid < N_GRAPHS) {
        float acc = bf2[0];
        #pragma unroll
        for (int c = 0; c < 32; ++c) acc += H4[tid][c] * Wf2[c];
        outp[tid] = acc;
    }
}

extern "C" void kernel_launch(void* const* d_in, const int* in_sizes, int n_in,
                              void* d_out, int out_size, void* d_ws, size_t ws_size,
                              hipStream_t stream) {
    const float* x    = (const float*)d_in[0];
    const int*   ei   = (const int*)d_in[1];
    const int*   batch= (const int*)d_in[2];
    const float* W1l  = (const float*)d_in[3];
    const float* b1   = (const float*)d_in[4];
    const float* W1r  = (const float*)d_in[5];
    const float* W2l  = (const float*)d_in[6];
    const float* b2   = (const float*)d_in[7];
    const float* W2r  = (const float*)d_in[8];
    const float* W3l  = (const float*)d_in[9];
    const float* b3   = (const float*)d_in[10];
    const float* W3r  = (const float*)d_in[11];
    const float* Wf1  = (const float*)d_in[12];
    const float* bf1  = (const float*)d_in[13];
    const float* Wf2  = (const float*)d_in[14];
    const float* bf2  = (const float*)d_in[15];
    const int* srcI = ei;
    const int* dstI = ei + N_EDGES;

    char* base = (char*)d_ws;
    size_t o = 0;
    auto alloc = [&](size_t bytes) -> void* {
        void* p = base + o;
        o = (o + bytes + 255) & ~(size_t)255;
        return p;
    };
    int*   bcnt    = (int*)alloc((size_t)NBUCKETS * 4);
    int*   bbase   = (int*)alloc((size_t)(NBUCKETS + 1) * 4);
    int*   bcursor = (int*)alloc((size_t)NBUCKETS * 4);
    int*   off     = (int*)alloc((size_t)(N_NODES + 1) * 4);
    unsigned int* ebuf = (unsigned int*)alloc((size_t)N_EDGES * 4);
    int*   csr     = (int*)alloc((size_t)N_EDGES * 4);
    __hip_bfloat16* hA = (__hip_bfloat16*)alloc((size_t)N_PAD * HS * 2);
    __hip_bfloat16* hB = (__hip_bfloat16*)alloc((size_t)N_PAD * HS * 2);
    __hip_bfloat16* Wcat = (__hip_bfloat16*)alloc((size_t)3 * 96 * SC * 2);
    float* pooled = (float*)alloc((size_t)(N_GRAPHS * D + N_GRAPHS) * 4);
    float* cntg   = pooled + N_GRAPHS * D;

    // fused head: cvt + W pack + zero-init
    k_prep<<<(N_PAD * HS + 255) / 256, 256, 0, stream>>>(
        x, hA, W1l, W1r, W2l, W2r, W3l, W3r, Wcat, bcnt, pooled);

    const int EB = (N_EDGES + BIN_EPB - 1) / BIN_EPB;  // 196
    k_hist<<<EB, 256, 0, stream>>>(dstI, bcnt);
    k_bscan<<<1, 256, 0, stream>>>(bcnt, bbase, bcursor);
    k_bin<<<EB, 256, 0, stream>>>(srcI, dstI, bcursor, ebuf);
    k_fill2<<<NBUCKETS, 256, 0, stream>>>(ebuf, bbase, off, csr);

    const int LAYER_BLOCKS = N_PAD / 32;   // 1564

    unsigned int* hAu = (unsigned int*)hA;
    unsigned int* hBu = (unsigned int*)hB;

    k_layer<<<LAYER_BLOCKS, 256, 0, stream>>>(hAu, Wcat,            b1, off, csr, hB);
    k_layer<<<LAYER_BLOCKS, 256, 0, stream>>>(hBu, Wcat +  96 * SC, b2, off, csr, hA);
    k_layer<<<LAYER_BLOCKS, 256, 0, stream>>>(hAu, Wcat + 192 * SC, b3, off, csr, hB);

    k_pool<<<POOL_WAVES / 4, 256, 0, stream>>>(hBu, batch, pooled, cntg);
    k_mlp<<<1, 256, 0, stream>>>(pooled, cntg, Wf1, bf1, Wf2, bf2, (float*)d_out);
}

// Round 14
// 200.099 us; speedup vs baseline: 1.2411x; 1.0865x over previous
//
#include <hip/hip_runtime.h>
#include <hip/hip_bf16.h>

#define N_NODES 50000
#define N_PAD   50048   // padded to multiple of 64 rows
#define N_EDGES 800000
#define N_GRAPHS 64
#define D 90
#define HS  96    // dense h row stride (bf16)
#define HSD 48    // dense h row stride (dwords)
#define H8D 32    // fp8 h row stride (dwords) = 128 B: one L2 line per row
#define SC  192   // Wcat row stride (bf16): [Wl(96) | Wr(96)]

#define NBUCKETS 196    // ceil(N_NODES/256): 256 nodes per bucket
#define BSHIFT 8
#define BIN_EPB 4096    // edges per block in hist/bin

typedef __attribute__((ext_vector_type(8))) short bf16x8;
typedef __attribute__((ext_vector_type(4))) float f32x4;
typedef __attribute__((ext_vector_type(2))) float f32x2;
typedef __attribute__((ext_vector_type(4))) unsigned int u32x4;

__device__ __forceinline__ float bflo(unsigned int v) { return __uint_as_float(v << 16); }
__device__ __forceinline__ float bfhi(unsigned int v) { return __uint_as_float(v & 0xffff0000u); }
__device__ __forceinline__ unsigned short bf16bits(float f) {
    __hip_bfloat16 b = __float2bfloat16(f);
    return *(unsigned short*)&b;
}
__device__ __forceinline__ unsigned int pack2bf(float lo, float hi) {
    return (unsigned int)bf16bits(lo) | ((unsigned int)bf16bits(hi) << 16);
}
// fp8 e4m3 HW convert (proven in R12: pack+unpack self-consistent, absmax unchanged)
__device__ __forceinline__ unsigned char f32_to_fp8(float v) {
    int pk = __builtin_amdgcn_cvt_pk_fp8_f32(v, v, 0, false);
    return (unsigned char)(pk & 0xff);
}
__device__ __forceinline__ void acc_fp8_dword(float* a, unsigned int u) {
    f32x2 lo = __builtin_amdgcn_cvt_pk_f32_fp8((int)u, false);
    f32x2 hi = __builtin_amdgcn_cvt_pk_f32_fp8((int)u, true);
    a[0] += lo.x; a[1] += lo.y; a[2] += hi.x; a[3] += hi.y;
}

// ---------------- fused head: x->bf16 h + fp8 h (128B rows), W pack, zero-init ----------------
__global__ void k_prep(const float* __restrict__ x, __hip_bfloat16* __restrict__ h0,
                       unsigned char* __restrict__ h8a, unsigned char* __restrict__ h8b,
                       const float* __restrict__ w1l, const float* __restrict__ w1r,
                       const float* __restrict__ w2l, const float* __restrict__ w2r,
                       const float* __restrict__ w3l, const float* __restrict__ w3r,
                       __hip_bfloat16* __restrict__ Wcat,
                       int* __restrict__ bcnt, float* __restrict__ pooled) {
    int idx = blockIdx.x * 256 + threadIdx.x;
    if (idx < N_PAD * 128) {
        int n = idx >> 7, j = idx & 127;
        float v = (n < N_NODES && j < D) ? x[n * D + j] : 0.f;
        h8a[idx] = f32_to_fp8(v);
        h8b[idx] = 0;   // zero pads; layer epilogue fills cols 0..95
    }
    if (idx < N_PAD * HS) {
        int n = idx / HS, k = idx - n * HS;
        float v = (n < N_NODES && k < D) ? x[n * D + k] : 0.f;
        h0[idx] = __float2bfloat16(v);
    }
    if (idx < 3 * 96 * SC) {
        const int per = 96 * SC;
        int layer = idx / per, rem = idx - layer * per;
        int j = rem / SC, k = rem - j * SC;
        const float* wl = (layer == 0) ? w1l : (layer == 1) ? w2l : w3l;
        const float* wr = (layer == 0) ? w1r : (layer == 1) ? w2r : w3r;
        float v = 0.f;
        if (j < D) {
            if (k < 96) { if (k < D) v = wl[j * D + k]; }
            else        { int kk = k - 96; if (kk < D) v = wr[j * D + kk]; }
        }
        Wcat[idx] = __float2bfloat16(v);
    }
    if (idx < N_GRAPHS * D + N_GRAPHS) pooled[idx] = 0.f;
    if (idx < NBUCKETS) bcnt[idx] = 0;
}

// ---------------- CSR build: bucket-local, write-coalesced ----------------
__global__ void k_hist(const int* __restrict__ dst, int* __restrict__ bcnt) {
    __shared__ int h[NBUCKETS];
    int t = threadIdx.x;
    for (int i = t; i < NBUCKETS; i += 256) h[i] = 0;
    __syncthreads();
    int base = blockIdx.x * BIN_EPB;
    int lim = base + BIN_EPB; if (lim > N_EDGES) lim = N_EDGES;
    for (int e = base + t; e < lim; e += 256)
        atomicAdd(&h[dst[e] >> BSHIFT], 1);
    __syncthreads();
    for (int i = t; i < NBUCKETS; i += 256) {
        int c = h[i];
        if (c) atomicAdd(&bcnt[i], c);
    }
}

__global__ void k_bscan(const int* __restrict__ bcnt, int* __restrict__ bbase,
                        int* __restrict__ bcursor) {
    __shared__ int s[256];
    int t = threadIdx.x;
    int v = (t < NBUCKETS) ? bcnt[t] : 0;
    s[t] = v; __syncthreads();
    for (int o = 1; o < 256; o <<= 1) {
        int x = (t >= o) ? s[t - o] : 0;
        __syncthreads();
        s[t] += x;
        __syncthreads();
    }
    int excl = s[t] - v;
    if (t < NBUCKETS) { bbase[t] = excl; bcursor[t] = excl; }
    if (t == 255) bbase[NBUCKETS] = s[255];   // total = N_EDGES
}

__global__ __launch_bounds__(256) void k_bin(const int* __restrict__ src,
                                             const int* __restrict__ dst,
                                             int* __restrict__ bcursor,
                                             unsigned int* __restrict__ ebuf) {
    __shared__ int h[NBUCKETS];
    __shared__ int gb[NBUCKETS];
    int t = threadIdx.x;
    for (int i = t; i < NBUCKETS; i += 256) h[i] = 0;
    __syncthreads();
    int base = blockIdx.x * BIN_EPB;
    int sv[16], dv[16], rv[16];
    #pragma unroll
    for (int i = 0; i < 16; ++i) {
        int e = base + i * 256 + t;
        if (e < N_EDGES) {
            sv[i] = src[e];
            dv[i] = dst[e];
            rv[i] = atomicAdd(&h[dv[i] >> BSHIFT], 1);
        }
    }
    __syncthreads();
    for (int i = t; i < NBUCKETS; i += 256)
        gb[i] = h[i] ? atomicAdd(&bcursor[i], h[i]) : 0;
    __syncthreads();
    #pragma unroll
    for (int i = 0; i < 16; ++i) {
        int e = base + i * 256 + t;
        if (e < N_EDGES) {
            int b = dv[i] >> BSHIFT;
            ebuf[gb[b] + rv[i]] = (unsigned int)sv[i] | ((unsigned int)(dv[i] & 255) << 16);
        }
    }
}

__global__ __launch_bounds__(256) void k_fill2(const unsigned int* __restrict__ ebuf,
                                               const int* __restrict__ bbase,
                                               int* __restrict__ off,
                                               int* __restrict__ csr) {
    __shared__ int lcnt[256];
    __shared__ int excl[256];
    int t = threadIdx.x;
    int n0 = blockIdx.x << BSHIFT;
    int ebeg = bbase[blockIdx.x], eend = bbase[blockIdx.x + 1];
    lcnt[t] = 0;
    __syncthreads();
    for (int e = ebeg + t; e < eend; e += 256)
        atomicAdd(&lcnt[ebuf[e] >> 16], 1);
    __syncthreads();
    int v = lcnt[t];
    excl[t] = v; __syncthreads();
    for (int o = 1; o < 256; o <<= 1) {
        int x = (t >= o) ? excl[t - o] : 0;
        __syncthreads();
        excl[t] += x;
        __syncthreads();
    }
    excl[t] -= v;           // exclusive prefix within bucket
    int n = n0 + t;
    if (n <= N_NODES) off[n] = ebeg + excl[t];
    lcnt[t] = 0;
    __syncthreads();
    for (int e = ebeg + t; e < eend; e += 256) {
        unsigned int u = ebuf[e];
        int li = u >> 16;
        int r = atomicAdd(&lcnt[li], 1);
        csr[ebeg + excl[li] + r] = (int)(u & 0xFFFFu);
    }
}

// ---------------- fused SAGE layer: fp8 1-line gather + MFMA + bias + ReLU ----------------
// block = 32 nodes, 256 threads (4 waves).
// Phase 1: each 8-lane group owns ONE node (8 concurrent chains/wave). Edge gather
//          = ONE 128B line: lane sl loads dwordx4 at h8[src*128 + 16*sl] (cols
//          16sl..16sl+15; sl>=6 reads zero pad). Unroll 4. HW fp8->f32 unpack.
// Phase 2: wave w = (strip w&1, col-half w>>1): 16 rows x 48 cols, 3 col-tiles x
//          6 k-steps MFMA. A k<96 from LDS (agg), k>=96 from global bf16 h.
// Epilogue: write bf16 hout + fp8 shadow hout8 (cols 0..95; pads pre-zeroed).
__global__ __launch_bounds__(256) void k_layer(
    const unsigned int* __restrict__ hin,   // [N_PAD][48] dwords (bf16 h)
    const unsigned int* __restrict__ hin8,  // [N_PAD][32] dwords (fp8 h, 128B rows)
    const __hip_bfloat16* __restrict__ Wcat,// [96][192]
    const float* __restrict__ bias,         // [90]
    const int* __restrict__ off, const int* __restrict__ csr,
    __hip_bfloat16* __restrict__ hout,      // [N_PAD][96]
    unsigned char* __restrict__ hout8)      // [N_PAD][128]
{
    __shared__ unsigned int aggT[32][52];
    __shared__ float biasPad[96];
    int tid = threadIdx.x;
    if (tid < 96) biasPad[tid] = (tid < D) ? bias[tid] : 0.f;
    int w = tid >> 6, lane = tid & 63;

    // ---- phase 1: node-per-group fp8 aggregation ----
    int grp = lane >> 3, sl = lane & 7;
    int local = w * 8 + grp;               // node slot 0..31
    int node = blockIdx.x * 32 + local;

    int beg = 0, end = 0;
    if (node < N_NODES) { beg = off[node]; end = off[node + 1]; }

    const u32x4* h8v = (const u32x4*)hin8;  // row = 8 x u32x4; lane reads vec #sl

    float a[16];
    #pragma unroll
    for (int q = 0; q < 16; ++q) a[q] = 0.f;

    int e = beg;
    for (; e + 4 <= end; e += 4) {
        u32x4 U0 = h8v[csr[e]     * 8 + sl];
        u32x4 U1 = h8v[csr[e + 1] * 8 + sl];
        u32x4 U2 = h8v[csr[e + 2] * 8 + sl];
        u32x4 U3 = h8v[csr[e + 3] * 8 + sl];
        #pragma unroll
        for (int q = 0; q < 4; ++q) acc_fp8_dword(&a[4 * q], U0[q]);
        #pragma unroll
        for (int q = 0; q < 4; ++q) acc_fp8_dword(&a[4 * q], U1[q]);
        #pragma unroll
        for (int q = 0; q < 4; ++q) acc_fp8_dword(&a[4 * q], U2[q]);
        #pragma unroll
        for (int q = 0; q < 4; ++q) acc_fp8_dword(&a[4 * q], U3[q]);
    }
    for (; e < end; ++e) {
        u32x4 U0 = h8v[csr[e] * 8 + sl];
        #pragma unroll
        for (int q = 0; q < 4; ++q) acc_fp8_dword(&a[4 * q], U0[q]);
    }

    if (sl < 6) {   // lanes 6,7 hold pad-zero sums
        float inv = 1.0f / fmaxf((float)(end - beg), 1.0f);
        #pragma unroll
        for (int q = 0; q < 8; ++q) {
            int c0 = 16 * sl + 2 * q;
            float lo = (c0     < D) ? a[2 * q]     * inv : 0.f;
            float hi = (c0 + 1 < D) ? a[2 * q + 1] * inv : 0.f;
            aggT[local][8 * sl + q] = pack2bf(lo, hi);
        }
    }
    __syncthreads();

    // ---- phase 2: MFMA ----
    int w2 = w & 1, half = w >> 1;
    int mrow = lane & 15, kg = lane >> 4;
    int r0 = blockIdx.x * 32 + w2 * 16;
    int lrow = w2 * 16 + mrow;
    const short* Wp = (const short*)Wcat;
    const short* Hs = (const short*)hin;

    f32x4 acc[3];
    #pragma unroll
    for (int t = 0; t < 3; ++t) {
        int j = (half * 3 + t) * 16 + mrow;
        float b = biasPad[j];
        acc[t] = (f32x4){b, b, b, b};
    }

    #pragma unroll
    for (int ks = 0; ks < 6; ++ks) {
        bf16x8 afr;
        if (ks < 3) afr = *(const bf16x8*)&aggT[lrow][ks * 16 + kg * 4];
        else        afr = *(const bf16x8*)&Hs[(r0 + mrow) * HS + (ks - 3) * 32 + kg * 8];
        #pragma unroll
        for (int t = 0; t < 3; ++t) {
            int j = (half * 3 + t) * 16 + mrow;
            bf16x8 bfr = *(const bf16x8*)&Wp[j * SC + ks * 32 + kg * 8];
            acc[t] = __builtin_amdgcn_mfma_f32_16x16x32_bf16(afr, bfr, acc[t], 0, 0, 0);
        }
    }

    // C/D layout (m89): col = lane&15, row = (lane>>4)*4 + v
    int orow = r0 + kg * 4;
    #pragma unroll
    for (int t = 0; t < 3; ++t) {
        int j = (half * 3 + t) * 16 + mrow;
        #pragma unroll
        for (int v = 0; v < 4; ++v) {
            float val = (j < D) ? fmaxf(acc[t][v], 0.f) : 0.f;
            hout[(orow + v) * HS + j] = __float2bfloat16(val);
            hout8[(orow + v) * 128 + j] = f32_to_fp8(val);
        }
    }
}

// ---------------- graph mean pool: segmented reduction (batch sorted) ----------------
#define POOL_WAVES 4096
__global__ void k_pool(const unsigned int* __restrict__ h, const int* __restrict__ batch,
                       float* __restrict__ pooled, float* __restrict__ cntg) {
    int wid  = (blockIdx.x * blockDim.x + threadIdx.x) >> 6;
    int lane = threadIdx.x & 63;
    const int per = (N_NODES + POOL_WAVES - 1) / POOL_WAVES;  // 13
    int beg = wid * per;
    int end = beg + per; if (end > N_NODES) end = N_NODES;
    if (beg >= end) return;
    int cur = batch[beg];
    float a0 = 0.f, a1 = 0.f, c = 0.f;
    for (int n = beg; n < end; ++n) {
        int g = batch[n];
        if (g != cur) {
            if (lane < 45) {
                atomicAdd(&pooled[cur * D + 2 * lane], a0);
                atomicAdd(&pooled[cur * D + 2 * lane + 1], a1);
            }
            if (lane == 0) atomicAdd(&cntg[cur], c);
            a0 = a1 = c = 0.f;
            cur = g;
        }
        if (lane < 45) {
            unsigned int v = h[n * HSD + lane];
            a0 += bflo(v);
            a1 += bfhi(v);
        }
        c += 1.f;
    }
    if (lane < 45) {
        atomicAdd(&pooled[cur * D + 2 * lane], a0);
        atomicAdd(&pooled[cur * D + 2 * lane + 1], a1);
    }
    if (lane == 0) atomicAdd(&cntg[cur], c);
}

// ---------------- final MLP (single block) ----------------
__global__ void k_mlp(const float* __restrict__ pooled, const float* __restrict__ cntg,
                      const float* __restrict__ Wf1, const float* __restrict__ bf1,
                      const float* __restrict__ Wf2, const float* __restrict__ bf2,
                      float* __restrict__ outp) {
    __shared__ float P[N_GRAPHS][92];
    __shared__ float H4[N_GRAPHS][32];
    int tid = threadIdx.x;
    for (int idx = tid; idx < N_GRAPHS * D; idx += 256) {
        int g = idx / D, d = idx - g * D;
        P[g][d] = pooled[idx] / fmaxf(cntg[g], 1.0f);
    }
    __syncthreads();
    for (int idx = tid; idx < N_GRAPHS * 32; idx += 256) {
        int g = idx >> 5, c = idx & 31;
        float acc = bf1[c];
        for (int d = 0; d < D; ++d) acc += P[g][d] * Wf1[c * D + d];
        H4[g][c] = fmaxf(acc, 0.f);
    }
    __syncthreads();
    if (tid < N_GRAPHS) {
        float acc = bf2[0];
        #pragma unroll
        for (int c = 0; c < 32; ++c) acc += H4[tid][c] * Wf2[c];
        outp[tid] = acc;
    }
}

extern "C" void kernel_launch(void* const* d_in, const int* in_sizes, int n_in,
                              void* d_out, int out_size, void* d_ws, size_t ws_size,
                              hipStream_t stream) {
    const float* x    = (const float*)d_in[0];
    const int*   ei   = (const int*)d_in[1];
    const int*   batch= (const int*)d_in[2];
    const float* W1l  = (const float*)d_in[3];
    const float* b1   = (const float*)d_in[4];
    const float* W1r  = (const float*)d_in[5];
    const float* W2l  = (const float*)d_in[6];
    const float* b2   = (const float*)d_in[7];
    const float* W2r  = (const float*)d_in[8];
    const float* W3l  = (const float*)d_in[9];
    const float* b3   = (const float*)d_in[10];
    const float* W3r  = (const float*)d_in[11];
    const float* Wf1  = (const float*)d_in[12];
    const float* bf1  = (const float*)d_in[13];
    const float* Wf2  = (const float*)d_in[14];
    const float* bf2  = (const float*)d_in[15];
    const int* srcI = ei;
    const int* dstI = ei + N_EDGES;

    char* base = (char*)d_ws;
    size_t o = 0;
    auto alloc = [&](size_t bytes) -> void* {
        void* p = base + o;
        o = (o + bytes + 255) & ~(size_t)255;
        return p;
    };
    int*   bcnt    = (int*)alloc((size_t)NBUCKETS * 4);
    int*   bbase   = (int*)alloc((size_t)(NBUCKETS + 1) * 4);
    int*   bcursor = (int*)alloc((size_t)NBUCKETS * 4);
    int*   off     = (int*)alloc((size_t)(N_NODES + 1) * 4);
    unsigned int* ebuf = (unsigned int*)alloc((size_t)N_EDGES * 4);
    int*   csr     = (int*)alloc((size_t)N_EDGES * 4);
    __hip_bfloat16* hA = (__hip_bfloat16*)alloc((size_t)N_PAD * HS * 2);
    __hip_bfloat16* hB = (__hip_bfloat16*)alloc((size_t)N_PAD * HS * 2);
    unsigned char* h8A = (unsigned char*)alloc((size_t)N_PAD * 128);
    unsigned char* h8B = (unsigned char*)alloc((size_t)N_PAD * 128);
    __hip_bfloat16* Wcat = (__hip_bfloat16*)alloc((size_t)3 * 96 * SC * 2);
    float* pooled = (float*)alloc((size_t)(N_GRAPHS * D + N_GRAPHS) * 4);
    float* cntg   = pooled + N_GRAPHS * D;

    // fused head: cvt (bf16 + fp8-128B) + W pack + zero-init
    k_prep<<<(N_PAD * 128 + 255) / 256, 256, 0, stream>>>(
        x, hA, h8A, h8B, W1l, W1r, W2l, W2r, W3l, W3r, Wcat, bcnt, pooled);

    const int EB = (N_EDGES + BIN_EPB - 1) / BIN_EPB;  // 196
    k_hist<<<EB, 256, 0, stream>>>(dstI, bcnt);
    k_bscan<<<1, 256, 0, stream>>>(bcnt, bbase, bcursor);
    k_bin<<<EB, 256, 0, stream>>>(srcI, dstI, bcursor, ebuf);
    k_fill2<<<NBUCKETS, 256, 0, stream>>>(ebuf, bbase, off, csr);

    const int LAYER_BLOCKS = N_PAD / 32;   // 1564

    unsigned int* hAu  = (unsigned int*)hA;
    unsigned int* hBu  = (unsigned int*)hB;
    unsigned int* h8Au = (unsigned int*)h8A;
    unsigned int* h8Bu = (unsigned int*)h8B;

    k_layer<<<LAYER_BLOCKS, 256, 0, stream>>>(hAu, h8Au, Wcat,            b1, off, csr, hB, h8B);
    k_layer<<<LAYER_BLOCKS, 256, 0, stream>>>(hBu, h8Bu, Wcat +  96 * SC, b2, off, csr, hA, h8A);
    k_layer<<<LAYER_BLOCKS, 256, 0, stream>>>(hAu, h8Au, Wcat + 192 * SC, b3, off, csr, hB, h8B);

    k_pool<<<POOL_WAVES / 4, 256, 0, stream>>>(hBu, batch, pooled, cntg);
    k_mlp<<<1, 256, 0, stream>>>(pooled, cntg, Wf1, bf1, Wf2, bf2, (float*)d_out);
}